// Round 8
// baseline (293.270 us; speedup 1.0000x reference)
//
#include <hip/hip_runtime.h>
#include <hip/hip_bf16.h>
#include <stdint.h>

typedef __bf16 bf16;
typedef __bf16 bf16x4 __attribute__((ext_vector_type(4)));
typedef __bf16 bf16x8 __attribute__((ext_vector_type(8)));
typedef float f32x4 __attribute__((ext_vector_type(4)));
typedef float f32x16 __attribute__((ext_vector_type(16)));
// float4 with only 4B alignment guarantee (global gather of hr windows)
typedef float f32x4u __attribute__((ext_vector_type(4), aligned(4)));

#define D_MODEL 768
#define NUM_HEADS 48
#define HEAD_CH 16
#define INNER 2304
#define BATCH 2
#define SEQLEN 2048
#define M_ROWS (BATCH * SEQLEN)
#define HR_N 2088  // 2048 + slack, zero-filled past 2047
#define EPSF 1e-6f

// async global->LDS, 16B per lane. LDS dest must be wave-uniform base + lane*16.
__device__ inline void gload_lds16(const void* g, void* l) {
  __builtin_amdgcn_global_load_lds((__attribute__((address_space(1))) void*)(g),
                                   (__attribute__((address_space(3))) void*)(l),
                                   16, 0, 0);
}

// ---------------------------------------------------------------------------
// f32 -> bf16 convert (memory-bound, float4 in / bf16x4 out)
// ---------------------------------------------------------------------------
__global__ __launch_bounds__(256) void cvt_f32_bf16(
    const float* __restrict__ src, bf16* __restrict__ dst, int n4) {
  const int i = blockIdx.x * 256 + threadIdx.x;
  if (i < n4) {
    const float4 v = ((const float4*)src)[i];
    bf16x4 o;
    o[0] = (bf16)v.x; o[1] = (bf16)v.y; o[2] = (bf16)v.z; o[3] = (bf16)v.w;
    ((bf16x4*)dst)[i] = o;
  }
}

// ---------------------------------------------------------------------------
// hr[nh][i] = h[nh][2047 - i] for i<=2047 else 0  (reversed + zero pad)
// ---------------------------------------------------------------------------
__global__ __launch_bounds__(256) void hrev_k(const float* __restrict__ hg,
                                              float* __restrict__ hr) {
  const int nh = blockIdx.x;
  for (int i = threadIdx.x; i < HR_N; i += 256)
    hr[nh * HR_N + i] = (i <= 2047) ? hg[nh * SEQLEN + 2047 - i] : 0.f;
}

// ---------------------------------------------------------------------------
// GEMM: C[m,n] = sum_k A[m,k]*W[n,k] + bias[n] (+ skip[m,n]); A (M,K), W (N,K)
// m97 pattern: 128x128 tile, BK=32, 4 waves each 64x64, global_load_lds x16.
// ---------------------------------------------------------------------------
template <int NCOLS, bool ADD_SKIP, typename CT>
__global__ __launch_bounds__(256) void gemm_bt(
    const bf16* __restrict__ A, const bf16* __restrict__ W,
    const float* __restrict__ bias, const float* __restrict__ skip,
    CT* __restrict__ C, int K) {
  __shared__ __align__(16) bf16 As[128 * 32];
  __shared__ __align__(16) bf16 Bs[128 * 32];
  const int t = threadIdx.x;
  const int lane = t & 63, w = t >> 6;
  const int wm = (w >> 1) * 64, wn = (w & 1) * 64;
  const int row16 = lane & 15, quad = lane >> 4;
  const int m0 = blockIdx.x * 128, n0 = blockIdx.y * 128;

  f32x4 zero4 = {0.f, 0.f, 0.f, 0.f};
  f32x4 acc[4][4];
#pragma unroll
  for (int mi = 0; mi < 4; ++mi)
#pragma unroll
    for (int ni = 0; ni < 4; ++ni) acc[mi][ni] = zero4;

  const int arow = t >> 2;
  const int acol = (t & 3) * 8;
  const bf16* Ab = A + (size_t)m0 * K;
  const bf16* Wb = W + (size_t)n0 * K;

  for (int kt = 0; kt < K; kt += 32) {
    gload_lds16(Ab + (size_t)arow * K + kt + acol, As + t * 8);
    gload_lds16(Ab + (size_t)(64 + arow) * K + kt + acol, As + 2048 + t * 8);
    gload_lds16(Wb + (size_t)arow * K + kt + acol, Bs + t * 8);
    gload_lds16(Wb + (size_t)(64 + arow) * K + kt + acol, Bs + 2048 + t * 8);
    __syncthreads();

    bf16x8 af[4], wf[4];
#pragma unroll
    for (int mi = 0; mi < 4; ++mi)
      af[mi] = *(const bf16x8*)&As[(wm + mi * 16 + row16) * 32 + quad * 8];
#pragma unroll
    for (int ni = 0; ni < 4; ++ni)
      wf[ni] = *(const bf16x8*)&Bs[(wn + ni * 16 + row16) * 32 + quad * 8];
#pragma unroll
    for (int mi = 0; mi < 4; ++mi)
#pragma unroll
      for (int ni = 0; ni < 4; ++ni)
        acc[mi][ni] = __builtin_amdgcn_mfma_f32_16x16x32_bf16(
            af[mi], wf[ni], acc[mi][ni], 0, 0, 0);
    __syncthreads();
  }

#pragma unroll
  for (int mi = 0; mi < 4; ++mi) {
#pragma unroll
    for (int ni = 0; ni < 4; ++ni) {
      const int col = n0 + wn + ni * 16 + row16;
      const float bv = bias[col];
#pragma unroll
      for (int r = 0; r < 4; ++r) {
        const int row = m0 + wm + mi * 16 + quad * 4 + r;
        float v = acc[mi][ni][r] + bv;
        if (ADD_SKIP) v += skip[(size_t)row * NCOLS + col];
        C[(size_t)row * NCOLS + col] = (CT)v;
      }
    }
  }
}

// ---------------------------------------------------------------------------
// K+V causal width-3 conv: head ch 16..31 -> K (B,N,L,16); 32..47 -> V (B,N,16,L)
// ---------------------------------------------------------------------------
__global__ __launch_bounds__(256) void conv_kv(
    const bf16* __restrict__ u, const float* __restrict__ w_sf,
    const float* __restrict__ b_sf, bf16* __restrict__ kk,
    bf16* __restrict__ vv) {
  const int nh = blockIdx.x, b = blockIdx.y, lc = blockIdx.z;
  const int l0 = lc * 128;
  __shared__ __align__(8) bf16 ut[130 * 32];
  const int t = threadIdx.x;
  for (int i = t; i < 130 * 8; i += 256) {
    const int lr = i >> 3, qd = i & 7;
    const int l = l0 - 2 + lr;
    uint2 val;
    val.x = 0u; val.y = 0u;
    if (l >= 0)
      val = *(const uint2*)&u[(size_t)(b * SEQLEN + l) * INNER + nh * 48 + 16 + qd * 4];
    *(uint2*)&ut[lr * 32 + qd * 4] = val;
  }
  __syncthreads();
  const size_t bn = (size_t)(b * NUM_HEADS + nh);
  for (int i = t; i < 128 * 16; i += 256) {
    const int c = i & 15, lr = i >> 4;
    const int e = nh * 48 + 16 + c;
    const float val = w_sf[e * 3 + 0] * (float)ut[lr * 32 + c] +
                      w_sf[e * 3 + 1] * (float)ut[(lr + 1) * 32 + c] +
                      w_sf[e * 3 + 2] * (float)ut[(lr + 2) * 32 + c] + b_sf[e];
    kk[(bn * SEQLEN + l0 + lr) * 16 + c] = (bf16)val;
  }
  for (int i = t; i < 128 * 16; i += 256) {
    const int lr = i & 127, c = i >> 7;
    const int e = nh * 48 + 32 + c;
    const float val = w_sf[e * 3 + 0] * (float)ut[lr * 32 + 16 + c] +
                      w_sf[e * 3 + 1] * (float)ut[(lr + 1) * 32 + 16 + c] +
                      w_sf[e * 3 + 2] * (float)ut[(lr + 2) * 32 + 16 + c] + b_sf[e];
    vv[(bn * 16 + c) * SEQLEN + l0 + lr] = (bf16)val;
  }
}

// ---------------------------------------------------------------------------
// Causal h-weighted attention v5: LDS-free K-loop.
// S^T = mfma_32x32x16(K,Q): lane l31 holds S[l=l31][m in regs] -- already a
// valid A-operand for PV (M=l, K=m) under a k-slot permutation pi, which is
// absorbed into V's load addresses (B uses the same pi). PV = 2x mfma_32x32x16
// (N=32, only 16 cols used). h prefetched into regs one step ahead.
// Grid (48, 2, 64) z-reversed; 4 waves KV-split stride 128; LDS only for the
// final cross-wave O reduction.
// ---------------------------------------------------------------------------
__global__ __launch_bounds__(256) void attn_kernel(
    const bf16* __restrict__ u, const bf16* __restrict__ kk,
    const bf16* __restrict__ vv, const float* __restrict__ w_sf,
    const float* __restrict__ b_sf, const float* __restrict__ hr,
    float* __restrict__ y) {
  const int nh = blockIdx.x, b = blockIdx.y;
  const int q32 = (int)gridDim.z - 1 - (int)blockIdx.z;  // big tiles first
  const int l0 = q32 * 32;
  __shared__ float ored[4][32 * 16];  // per-wave O for cross-wave reduce (8KB)
  const int t = threadIdx.x;
  const int w = t >> 6, lane = t & 63;
  const int l31 = lane & 31, hi = lane >> 5;
  const bf16* ub = u + (size_t)b * SEQLEN * INNER;
  const size_t bn = (size_t)(b * NUM_HEADS + nh);
  const bf16* kb = kk + bn * SEQLEN * 16;
  const bf16* vrow = vv + bn * 16 * SEQLEN + (size_t)(l31 & 15) * SEQLEN;
  const float* hrb = hr + nh * HR_N;

  bf16x8 zf;
#pragma unroll
  for (int j = 0; j < 8; ++j) zf[j] = (bf16)0.f;
  bf16x4 zf4;
#pragma unroll
  for (int j = 0; j < 4; ++j) zf4[j] = (bf16)0.f;
  f32x16 zacc16;
#pragma unroll
  for (int j = 0; j < 16; ++j) zacc16[j] = 0.f;
  const f32x4 zh = {0.f, 0.f, 0.f, 0.f};

  // ---- fused Q conv: Q[l0+l31][ch hi*8..+8] (B-operand for QK) ----
  bf16x8 qf;
  {
    const int cq = nh * 48 + hi * 8;
    const int l = l0 + l31;
    bf16x8 t2 = *(const bf16x8*)&ub[(size_t)l * INNER + cq];
    bf16x8 t1 = (l >= 1) ? *(const bf16x8*)&ub[(size_t)(l - 1) * INNER + cq] : zf;
    bf16x8 t0 = (l >= 2) ? *(const bf16x8*)&ub[(size_t)(l - 2) * INNER + cq] : zf;
#pragma unroll
    for (int j = 0; j < 8; ++j)
      qf[j] = (bf16)(w_sf[(cq + j) * 3 + 0] * (float)t0[j] +
                     w_sf[(cq + j) * 3 + 1] * (float)t1[j] +
                     w_sf[(cq + j) * 3 + 2] * (float)t2[j] + b_sf[cq + j]);
  }

  f32x16 o = zacc16;
  const int mc0 = w * 32;
  // h base for step mc: index i = hb0 + (mc - mc0) + 8g + j  (hr reversed)
  int hb = 2047 - (l0 - mc0) - l31 + 4 * hi;

  // prefetch registers for current step
  bf16x8 kf = zf;
  f32x4 hv[4] = {zh, zh, zh, zh};
  bf16x4 vfr[4] = {zf4, zf4, zf4, zf4};
  if (mc0 <= l0) {
    kf = *(const bf16x8*)&kb[(mc0 + l31) * 16 + hi * 8];
#pragma unroll
    for (int g = 0; g < 4; ++g) {
      hv[g] = (f32x4)(*(const f32x4u*)&hrb[hb + 8 * g]);
      vfr[g] = *(const bf16x4*)&vrow[mc0 + 4 * hi + 8 * g];
    }
  }

  for (int mc = mc0; mc <= l0; mc += 128) {
    const int mn = mc + 128;
    bf16x8 kfn = zf;
    f32x4 hvn[4] = {zh, zh, zh, zh};
    bf16x4 vfn[4] = {zf4, zf4, zf4, zf4};
    if (mn <= l0) {  // prefetch next step
      kfn = *(const bf16x8*)&kb[(mn + l31) * 16 + hi * 8];
#pragma unroll
      for (int g = 0; g < 4; ++g) {
        hvn[g] = (f32x4)(*(const f32x4u*)&hrb[hb + 128 + 8 * g]);
        vfn[g] = *(const bf16x4*)&vrow[mn + 4 * hi + 8 * g];
      }
    }
    // S^T: lane l31 = col l, regs = m (m_loc = 4hi + 8g + j)
    f32x16 s = __builtin_amdgcn_mfma_f32_32x32x16_bf16(kf, qf, zacc16, 0, 0, 0);

    // h-weight (causal via hr zero-pad) + pack into PV A-operands:
    // a0 = groups g0,g1 (m 4hi..4hi+3, 8+4hi..+3), a1 = g2,g3 (+16)
    bf16x8 a0, a1;
#pragma unroll
    for (int g = 0; g < 4; ++g) {
      const f32x4 h4 = hv[g];
#pragma unroll
      for (int j = 0; j < 4; ++j) {
        const float v = s[4 * g + j] * h4[j];
        if (g < 2) a0[4 * (g & 1) + j] = (bf16)v;
        else       a1[4 * (g & 1) + j] = (bf16)v;
      }
    }
    // B-operands (V under the same k-slot permutation):
    // slot k=hi*8+jj -> m = 4hi + 8*(jj>>2) + (jj&3)  [+16 for half1]
    bf16x8 b0, b1;
#pragma unroll
    for (int j = 0; j < 4; ++j) {
      b0[j] = vfr[0][j]; b0[4 + j] = vfr[1][j];
      b1[j] = vfr[2][j]; b1[4 + j] = vfr[3][j];
    }
    o = __builtin_amdgcn_mfma_f32_32x32x16_bf16(a0, b0, o, 0, 0, 0);
    o = __builtin_amdgcn_mfma_f32_32x32x16_bf16(a1, b1, o, 0, 0, 0);

    kf = kfn;
#pragma unroll
    for (int g = 0; g < 4; ++g) { hv[g] = hvn[g]; vfr[g] = vfn[g]; }
    hb += 128;
  }

  // o: lane (l31,hi) reg r holds y[l = (r&3)+8*(r>>2)+4hi][j = l31], j<16 valid
  if (l31 < 16) {
#pragma unroll
    for (int r = 0; r < 16; ++r) {
      const int lloc = (r & 3) + 8 * (r >> 2) + 4 * hi;
      ored[w][lloc * 16 + l31] = o[r];
    }
  }
  __syncthreads();
  for (int i = t; i < 32 * 16; i += 256) {
    const int l = i >> 4, j = i & 15;
    const float sum = ored[0][i] + ored[1][i] + ored[2][i] + ored[3][i];
    y[((size_t)(b * SEQLEN + l0 + l) * NUM_HEADS + nh) * 16 + j] = sum;
  }
}

// ---------------------------------------------------------------------------
// RMSNorm over D=768 per row: y f32 in, yn bf16 out, * norm_w (f32)
// ---------------------------------------------------------------------------
__global__ __launch_bounds__(256) void rmsnorm_k(
    const float* __restrict__ y, const float* __restrict__ nw,
    bf16* __restrict__ yn) {
  const int row = blockIdx.x;
  const int t = threadIdx.x;
  const float* yr = y + (size_t)row * D_MODEL;
  const float v0 = yr[t];
  const float v1 = yr[t + 256];
  const float v2 = yr[t + 512];
  float ss = v0 * v0 + v1 * v1 + v2 * v2;
#pragma unroll
  for (int off = 32; off >= 1; off >>= 1) ss += __shfl_down(ss, off, 64);
  __shared__ float red[4];
  if ((t & 63) == 0) red[t >> 6] = ss;
  __syncthreads();
  const float tot = red[0] + red[1] + red[2] + red[3];
  const float r = rsqrtf(tot * (1.f / 768.f) + EPSF);
  bf16* yo = yn + (size_t)row * D_MODEL;
  yo[t] = (bf16)(v0 * r * nw[t]);
  yo[t + 256] = (bf16)(v1 * r * nw[t + 256]);
  yo[t + 512] = (bf16)(v2 * r * nw[t + 512]);
}

// ---------------------------------------------------------------------------
extern "C" void kernel_launch(void* const* d_in, const int* in_sizes, int n_in,
                              void* d_out, int out_size, void* d_ws,
                              size_t ws_size, hipStream_t stream) {
  const float* inputs = (const float*)d_in[0];
  const float* w_in = (const float*)d_in[1];
  const float* b_in = (const float*)d_in[2];
  const float* w_sf = (const float*)d_in[3];
  const float* b_sf = (const float*)d_in[4];
  const float* hb = (const float*)d_in[5];
  const float* norm_w = (const float*)d_in[6];
  const float* w_out = (const float*)d_in[7];
  const float* b_out = (const float*)d_in[8];

  // ws plan (~36.6 MB):
  //   u      18.9 MB bf16   (alive through attn: Q-conv reads it)
  //   v       6.3 MB bf16
  //   slot    6.3 MB bf16   (in16 for GEMM1 -> k for attn -> yn for GEMM2)
  //   win16   3.5 MB bf16
  //   wout16  1.2 MB bf16
  //   hr      0.4 MB f32    (reversed zero-padded h per head)
  // y (f32) lives in d_out (dead after rmsnorm, overwritten by GEMM2).
  char* ws = (char*)d_ws;
  const size_t U_B = (size_t)M_ROWS * INNER * 2;
  const size_t V_B = (size_t)BATCH * NUM_HEADS * HEAD_CH * SEQLEN * 2;
  const size_t SLOT_B = (size_t)M_ROWS * D_MODEL * 2;
  const size_t WIN_B = (size_t)INNER * D_MODEL * 2;
  const size_t WOUT_B = (size_t)D_MODEL * D_MODEL * 2;
  bf16* u = (bf16*)(ws);
  bf16* v = (bf16*)(ws + U_B);
  bf16* in16 = (bf16*)(ws + U_B + V_B);
  bf16* k16 = in16;  // in16 dead after GEMM1
  bf16* yn = in16;   // k dead after attn
  bf16* win16 = (bf16*)(ws + U_B + V_B + SLOT_B);
  bf16* wout16 = (bf16*)(ws + U_B + V_B + SLOT_B + WIN_B);
  float* hr = (float*)(ws + U_B + V_B + SLOT_B + WIN_B + WOUT_B);
  float* y = (float*)d_out;
  float* out = (float*)d_out;

  const int n4_in = M_ROWS * D_MODEL / 4;
  const int n4_win = INNER * D_MODEL / 4;
  const int n4_wout = D_MODEL * D_MODEL / 4;
  hipLaunchKernelGGL(cvt_f32_bf16, dim3((n4_in + 255) / 256), dim3(256), 0,
                     stream, inputs, in16, n4_in);
  hipLaunchKernelGGL(cvt_f32_bf16, dim3((n4_win + 255) / 256), dim3(256), 0,
                     stream, w_in, win16, n4_win);
  hipLaunchKernelGGL(cvt_f32_bf16, dim3((n4_wout + 255) / 256), dim3(256), 0,
                     stream, w_out, wout16, n4_wout);
  hipLaunchKernelGGL(hrev_k, dim3(NUM_HEADS), dim3(256), 0, stream, hb, hr);

  hipLaunchKernelGGL((gemm_bt<INNER, false, bf16>), dim3(32, 18), dim3(256), 0,
                     stream, in16, win16, b_in, (const float*)nullptr, u, 768);
  hipLaunchKernelGGL(conv_kv, dim3(48, 2, 16), dim3(256), 0, stream, u, w_sf,
                     b_sf, k16, v);
  hipLaunchKernelGGL(attn_kernel, dim3(48, 2, 64), dim3(256), 0, stream, u,
                     k16, v, w_sf, b_sf, hr, y);
  hipLaunchKernelGGL(rmsnorm_k, dim3(M_ROWS), dim3(256), 0, stream, y, norm_w,
                     yn);
  hipLaunchKernelGGL((gemm_bt<D_MODEL, true, float>), dim3(32, 6), dim3(256),
                     0, stream, yn, wout16, b_out, inputs, out, 768);
}

// Round 9
// 206.617 us; speedup vs baseline: 1.4194x; 1.4194x over previous
//
#include <hip/hip_runtime.h>
#include <hip/hip_bf16.h>
#include <stdint.h>

typedef __bf16 bf16;
typedef __bf16 bf16x4 __attribute__((ext_vector_type(4)));
typedef __bf16 bf16x8 __attribute__((ext_vector_type(8)));
typedef float f32x4 __attribute__((ext_vector_type(4)));
typedef float f32x16 __attribute__((ext_vector_type(16)));

#define D_MODEL 768
#define NUM_HEADS 48
#define HEAD_CH 16
#define INNER 2304
#define BATCH 2
#define SEQLEN 2048
#define M_ROWS (BATCH * SEQLEN)
#define EPSF 1e-6f

// async global->LDS, 16B per lane. LDS dest must be wave-uniform base + lane*16.
__device__ inline void gload_lds16(const void* g, void* l) {
  __builtin_amdgcn_global_load_lds((__attribute__((address_space(1))) void*)(g),
                                   (__attribute__((address_space(3))) void*)(l),
                                   16, 0, 0);
}

// ---------------------------------------------------------------------------
// f32 -> bf16 convert (memory-bound, float4 in / bf16x4 out)
// ---------------------------------------------------------------------------
__global__ __launch_bounds__(256) void cvt_f32_bf16(
    const float* __restrict__ src, bf16* __restrict__ dst, int n4) {
  const int i = blockIdx.x * 256 + threadIdx.x;
  if (i < n4) {
    const float4 v = ((const float4*)src)[i];
    bf16x4 o;
    o[0] = (bf16)v.x; o[1] = (bf16)v.y; o[2] = (bf16)v.z; o[3] = (bf16)v.w;
    ((bf16x4*)dst)[i] = o;
  }
}

// ---------------------------------------------------------------------------
// GEMM: C[m,n] = sum_k A[m,k]*W[n,k] + bias[n] (+ skip[m,n]); A (M,K), W (N,K)
// m97 pattern, TM x 128 tile (TM=128 or 64), BK=32, 4 waves.
// TM=128: waves 64x64 each; TM=64: waves 32x64 each (grid 2x denser).
// ---------------------------------------------------------------------------
template <int TM, int NCOLS, bool ADD_SKIP, typename CT>
__global__ __launch_bounds__(256) void gemm_bt(
    const bf16* __restrict__ A, const bf16* __restrict__ W,
    const float* __restrict__ bias, const float* __restrict__ skip,
    CT* __restrict__ C, int K) {
  constexpr int MI = TM / 32;  // m-frags per wave
  __shared__ __align__(16) bf16 As[TM * 32];
  __shared__ __align__(16) bf16 Bs[128 * 32];
  const int t = threadIdx.x;
  const int lane = t & 63, w = t >> 6;
  const int wm = (w >> 1) * (TM / 2), wn = (w & 1) * 64;
  const int row16 = lane & 15, quad = lane >> 4;
  const int m0 = blockIdx.x * TM, n0 = blockIdx.y * 128;

  f32x4 zero4 = {0.f, 0.f, 0.f, 0.f};
  f32x4 acc[MI][4];
#pragma unroll
  for (int mi = 0; mi < MI; ++mi)
#pragma unroll
    for (int ni = 0; ni < 4; ++ni) acc[mi][ni] = zero4;

  const int arow = t >> 2;
  const int acol = (t & 3) * 8;
  const bf16* Ab = A + (size_t)m0 * K;
  const bf16* Wb = W + (size_t)n0 * K;

  for (int kt = 0; kt < K; kt += 32) {
    gload_lds16(Ab + (size_t)arow * K + kt + acol, As + t * 8);
    if (TM == 128)
      gload_lds16(Ab + (size_t)(64 + arow) * K + kt + acol, As + 2048 + t * 8);
    gload_lds16(Wb + (size_t)arow * K + kt + acol, Bs + t * 8);
    gload_lds16(Wb + (size_t)(64 + arow) * K + kt + acol, Bs + 2048 + t * 8);
    __syncthreads();

    bf16x8 af[MI], wf[4];
#pragma unroll
    for (int mi = 0; mi < MI; ++mi)
      af[mi] = *(const bf16x8*)&As[(wm + mi * 16 + row16) * 32 + quad * 8];
#pragma unroll
    for (int ni = 0; ni < 4; ++ni)
      wf[ni] = *(const bf16x8*)&Bs[(wn + ni * 16 + row16) * 32 + quad * 8];
#pragma unroll
    for (int mi = 0; mi < MI; ++mi)
#pragma unroll
      for (int ni = 0; ni < 4; ++ni)
        acc[mi][ni] = __builtin_amdgcn_mfma_f32_16x16x32_bf16(
            af[mi], wf[ni], acc[mi][ni], 0, 0, 0);
    __syncthreads();
  }

#pragma unroll
  for (int mi = 0; mi < MI; ++mi) {
#pragma unroll
    for (int ni = 0; ni < 4; ++ni) {
      const int col = n0 + wn + ni * 16 + row16;
      const float bv = bias[col];
#pragma unroll
      for (int r = 0; r < 4; ++r) {
        const int row = m0 + wm + mi * 16 + quad * 4 + r;
        float v = acc[mi][ni][r] + bv;
        if (ADD_SKIP) v += skip[(size_t)row * NCOLS + col];
        C[(size_t)row * NCOLS + col] = (CT)v;
      }
    }
  }
}

// ---------------------------------------------------------------------------
// Q+K+V causal width-3 conv from u:
//   ch 0..15  -> Q (B,N,L,16);  16..31 -> K (B,N,L,16);  32..47 -> V (B,N,16,L)
// ---------------------------------------------------------------------------
__global__ __launch_bounds__(256) void conv_qkv(
    const bf16* __restrict__ u, const float* __restrict__ w_sf,
    const float* __restrict__ b_sf, bf16* __restrict__ qq,
    bf16* __restrict__ kk, bf16* __restrict__ vv) {
  const int nh = blockIdx.x, b = blockIdx.y, lc = blockIdx.z;
  const int l0 = lc * 128;
  __shared__ __align__(8) bf16 ut[130 * 48];
  const int t = threadIdx.x;
  for (int i = t; i < 130 * 12; i += 256) {
    const int lr = i / 12, qd = i % 12;
    const int l = l0 - 2 + lr;
    uint2 val;
    val.x = 0u; val.y = 0u;
    if (l >= 0)
      val = *(const uint2*)&u[(size_t)(b * SEQLEN + l) * INNER + nh * 48 + qd * 4];
    *(uint2*)&ut[lr * 48 + qd * 4] = val;
  }
  __syncthreads();
  const size_t bn = (size_t)(b * NUM_HEADS + nh);
  // Q (ch 0..15) and K (ch 16..31): (B,N,L,16), channel fastest
#pragma unroll
  for (int s = 0; s < 2; ++s) {
    bf16* dst = (s == 0) ? qq : kk;
    const int cb = s * 16;
    for (int i = t; i < 128 * 16; i += 256) {
      const int c = i & 15, lr = i >> 4;
      const int e = nh * 48 + cb + c;
      const float val = w_sf[e * 3 + 0] * (float)ut[lr * 48 + cb + c] +
                        w_sf[e * 3 + 1] * (float)ut[(lr + 1) * 48 + cb + c] +
                        w_sf[e * 3 + 2] * (float)ut[(lr + 2) * 48 + cb + c] +
                        b_sf[e];
      dst[(bn * SEQLEN + l0 + lr) * 16 + c] = (bf16)val;
    }
  }
  // V (ch 32..47): (B,N,16,L), l fastest
  for (int i = t; i < 128 * 16; i += 256) {
    const int lr = i & 127, c = i >> 7;
    const int e = nh * 48 + 32 + c;
    const float val = w_sf[e * 3 + 0] * (float)ut[lr * 48 + 32 + c] +
                      w_sf[e * 3 + 1] * (float)ut[(lr + 1) * 48 + 32 + c] +
                      w_sf[e * 3 + 2] * (float)ut[(lr + 2) * 48 + 32 + c] +
                      b_sf[e];
    vv[(bn * 16 + c) * SEQLEN + l0 + lr] = (bf16)val;
  }
}

// ---------------------------------------------------------------------------
// Causal h-weighted attention v6 = r4 structure (best measured: 70.8us) with
// materialized Q (preamble = one 16B load) and trimmed hs fill.
// One 32-row Q tile per block, KV split 4 ways across waves (6144 blocks).
// S^T = mfma_32x32x16(K,Q); h-weight from LDS hs; S->A via LDS round-trip;
// PV = 2x mfma_16x16x32; cross-wave O reduce in LDS.
// ---------------------------------------------------------------------------
__global__ __launch_bounds__(256) void attn_kernel(
    const bf16* __restrict__ qq, const bf16* __restrict__ kk,
    const bf16* __restrict__ vv, const float* __restrict__ hg,
    float* __restrict__ y) {
  const int nh = blockIdx.x, b = blockIdx.y;
  const int q32 = (int)gridDim.z - 1 - (int)blockIdx.z;  // big tiles first
  const int l0 = q32 * 32;
  __shared__ __align__(16) float hs[SEQLEN];
  __shared__ __align__(16) bf16 st[4 * 32 * 40];  // per-wave S-tile / O-redux
  const int t = threadIdx.x;
  // fill only hs[0 .. l0+32): that's all this block's (l - m) can reach
  const int n4 = (l0 + 32) >> 2;
  for (int i = t; i < n4; i += 256)
    ((float4*)hs)[i] = ((const float4*)(hg + nh * SEQLEN))[i];
  __syncthreads();

  const int w = t >> 6, lane = t & 63;
  const int l31 = lane & 31, hi = lane >> 5;
  const int row16 = lane & 15, quad = lane >> 4;
  const size_t bn = (size_t)(b * NUM_HEADS + nh);
  const bf16* qb = qq + bn * SEQLEN * 16;
  const bf16* kb = kk + bn * SEQLEN * 16;
  const bf16* vb = vv + bn * 16 * SEQLEN;

  bf16x8 zf;
#pragma unroll
  for (int j = 0; j < 8; ++j) zf[j] = (bf16)0.f;
  const f32x4 zacc4 = {0.f, 0.f, 0.f, 0.f};
  f32x16 zacc16;
#pragma unroll
  for (int j = 0; j < 16; ++j) zacc16[j] = 0.f;

  // Q B-operand frag: lane l31 holds Q[l0+l31][ch hi*8..+8]
  const bf16x8 qf = *(const bf16x8*)&qb[(l0 + l31) * 16 + hi * 8];

  f32x4 o0 = zacc4, o1 = zacc4;
  bf16* sw = &st[w * 32 * 40];

  int mc = w * 32;
  bf16x8 kf = zf, vf = zf;
  if (mc <= l0) {
    kf = *(const bf16x8*)&kb[(mc + l31) * 16 + hi * 8];
    vf = *(const bf16x8*)&vb[row16 * SEQLEN + mc + quad * 8];
  }
  for (; mc <= l0; mc += 128) {
    const int mn = mc + 128;
    bf16x8 kf2 = zf, vf2 = zf;
    if (mn <= l0) {  // prefetch next chunk
      kf2 = *(const bf16x8*)&kb[(mn + l31) * 16 + hi * 8];
      vf2 = *(const bf16x8*)&vb[row16 * SEQLEN + mn + quad * 8];
    }
    // S^T[m-local=rows][l-local=cols] = sum_ch K*Q
    f32x16 s = __builtin_amdgcn_mfma_f32_32x32x16_bf16(kf, qf, zacc16, 0, 0, 0);

    // h-weight + causal mask, pack 4 rows -> b64 LDS store per group
    const int hb0 = (l0 - mc) + l31 - 4 * hi;
#pragma unroll
    for (int g = 0; g < 4; ++g) {
      const int d3 = hb0 - 8 * g;  // d for row (8g+4hi+3) is d3-3 ... row+0 is d3
      bf16x4 pk;
      {
        const int m = mc + 8 * g + 4 * hi;  // m for reg j=0
        pk[0] = (bf16)((m + 0 <= l0 + l31) ? s[4 * g + 0] * hs[d3 - 0] : 0.f);
        pk[1] = (bf16)((m + 1 <= l0 + l31) ? s[4 * g + 1] * hs[d3 - 1] : 0.f);
        pk[2] = (bf16)((m + 2 <= l0 + l31) ? s[4 * g + 2] * hs[d3 - 2] : 0.f);
        pk[3] = (bf16)((m + 3 <= l0 + l31) ? s[4 * g + 3] * hs[d3 - 3] : 0.f);
      }
      *(bf16x4*)&sw[l31 * 40 + 8 * g + 4 * hi] = pk;
    }
    asm volatile("s_waitcnt lgkmcnt(0)" ::: "memory");  // stores before reads
    // PV: A = S[l][m] (b128), B = V[m][j] frag (shared by both halves)
    const bf16x8 sf0 = *(const bf16x8*)&sw[row16 * 40 + quad * 8];
    const bf16x8 sf1 = *(const bf16x8*)&sw[(row16 + 16) * 40 + quad * 8];
    o0 = __builtin_amdgcn_mfma_f32_16x16x32_bf16(sf0, vf, o0, 0, 0, 0);
    o1 = __builtin_amdgcn_mfma_f32_16x16x32_bf16(sf1, vf, o1, 0, 0, 0);
    asm volatile("" ::: "memory");  // reads before next-iter stores
    kf = kf2; vf = vf2;
  }

  // per-wave O into own LDS region (f32 32x16), then block reduce
  float* ob = (float*)&st[w * 32 * 40];
#pragma unroll
  for (int r = 0; r < 4; ++r) {
    ob[(quad * 4 + r) * 16 + row16] = o0[r];
    ob[(quad * 4 + r + 16) * 16 + row16] = o1[r];
  }
  __syncthreads();
  for (int i = t; i < 32 * 16; i += 256) {
    const int l = i >> 4, j = i & 15;
    float sum = 0.f;
#pragma unroll
    for (int ww = 0; ww < 4; ++ww)
      sum += ((const float*)&st[ww * 32 * 40])[l * 16 + j];
    y[((size_t)(b * SEQLEN + l0 + l) * NUM_HEADS + nh) * 16 + j] = sum;
  }
}

// ---------------------------------------------------------------------------
// RMSNorm over D=768 per row: y f32 in, yn bf16 out, * norm_w (f32)
// ---------------------------------------------------------------------------
__global__ __launch_bounds__(256) void rmsnorm_k(
    const float* __restrict__ y, const float* __restrict__ nw,
    bf16* __restrict__ yn) {
  const int row = blockIdx.x;
  const int t = threadIdx.x;
  const float* yr = y + (size_t)row * D_MODEL;
  const float v0 = yr[t];
  const float v1 = yr[t + 256];
  const float v2 = yr[t + 512];
  float ss = v0 * v0 + v1 * v1 + v2 * v2;
#pragma unroll
  for (int off = 32; off >= 1; off >>= 1) ss += __shfl_down(ss, off, 64);
  __shared__ float red[4];
  if ((t & 63) == 0) red[t >> 6] = ss;
  __syncthreads();
  const float tot = red[0] + red[1] + red[2] + red[3];
  const float r = rsqrtf(tot * (1.f / 768.f) + EPSF);
  bf16* yo = yn + (size_t)row * D_MODEL;
  yo[t] = (bf16)(v0 * r * nw[t]);
  yo[t + 256] = (bf16)(v1 * r * nw[t + 256]);
  yo[t + 512] = (bf16)(v2 * r * nw[t + 512]);
}

// ---------------------------------------------------------------------------
extern "C" void kernel_launch(void* const* d_in, const int* in_sizes, int n_in,
                              void* d_out, int out_size, void* d_ws,
                              size_t ws_size, hipStream_t stream) {
  const float* inputs = (const float*)d_in[0];
  const float* w_in = (const float*)d_in[1];
  const float* b_in = (const float*)d_in[2];
  const float* w_sf = (const float*)d_in[3];
  const float* b_sf = (const float*)d_in[4];
  const float* hb = (const float*)d_in[5];
  const float* norm_w = (const float*)d_in[6];
  const float* w_out = (const float*)d_in[7];
  const float* b_out = (const float*)d_in[8];

  // ws plan (37.8 MB), region lifetimes:
  //   u   18.9 MB : GEMM1 out -> dead after conv_qkv; tail reused for
  //                 wout16 (at +0) and yn (at +2MB) late in the pipeline
  //   v    6.3 MB : V
  //   A    6.3 MB : in16 (GEMM1 A) -> k16 (attn) -> dead
  //   B    6.3 MB : win16 (GEMM1 W, 3.5MB) -> q16 (attn)
  char* ws = (char*)d_ws;
  const size_t U_B = (size_t)M_ROWS * INNER * 2;
  const size_t V_B = (size_t)BATCH * NUM_HEADS * HEAD_CH * SEQLEN * 2;
  const size_t SLOT_B = (size_t)M_ROWS * D_MODEL * 2;
  bf16* u = (bf16*)(ws);
  bf16* wout16 = (bf16*)(ws);                    // u region, after conv
  bf16* yn = (bf16*)(ws + (2 << 20));            // u region +2MB (wout=1.2MB)
  bf16* v = (bf16*)(ws + U_B);
  bf16* in16 = (bf16*)(ws + U_B + V_B);          // A
  bf16* k16 = in16;                              // A after GEMM1
  bf16* win16 = (bf16*)(ws + U_B + V_B + SLOT_B);// B
  bf16* q16 = win16;                             // B after GEMM1
  float* y = (float*)d_out;
  float* out = (float*)d_out;

  const int n4_in = M_ROWS * D_MODEL / 4;
  const int n4_win = INNER * D_MODEL / 4;
  const int n4_wout = D_MODEL * D_MODEL / 4;
  hipLaunchKernelGGL(cvt_f32_bf16, dim3((n4_in + 255) / 256), dim3(256), 0,
                     stream, inputs, in16, n4_in);
  hipLaunchKernelGGL(cvt_f32_bf16, dim3((n4_win + 255) / 256), dim3(256), 0,
                     stream, w_in, win16, n4_win);

  hipLaunchKernelGGL((gemm_bt<128, INNER, false, bf16>), dim3(32, 18),
                     dim3(256), 0, stream, in16, win16, b_in,
                     (const float*)nullptr, u, 768);
  hipLaunchKernelGGL(conv_qkv, dim3(48, 2, 16), dim3(256), 0, stream, u, w_sf,
                     b_sf, q16, k16, v);
  // u dead now: stage w_out into its head
  hipLaunchKernelGGL(cvt_f32_bf16, dim3((n4_wout + 255) / 256), dim3(256), 0,
                     stream, w_out, wout16, n4_wout);
  hipLaunchKernelGGL(attn_kernel, dim3(48, 2, 64), dim3(256), 0, stream, q16,
                     k16, v, hb, y);
  hipLaunchKernelGGL(rmsnorm_k, dim3(M_ROWS), dim3(256), 0, stream, y, norm_w,
                     yn);
  hipLaunchKernelGGL((gemm_bt<64, D_MODEL, true, float>), dim3(64, 6),
                     dim3(256), 0, stream, yn, wout16, b_out, inputs, out, 768);
}

// Round 10
// 190.445 us; speedup vs baseline: 1.5399x; 1.0849x over previous
//
#include <hip/hip_runtime.h>
#include <hip/hip_bf16.h>
#include <stdint.h>

typedef __bf16 bf16;
typedef __bf16 bf16x4 __attribute__((ext_vector_type(4)));
typedef __bf16 bf16x8 __attribute__((ext_vector_type(8)));
typedef float f32x4 __attribute__((ext_vector_type(4)));
typedef float f32x16 __attribute__((ext_vector_type(16)));

#define D_MODEL 768
#define NUM_HEADS 48
#define HEAD_CH 16
#define INNER 2304
#define BATCH 2
#define SEQLEN 2048
#define M_ROWS (BATCH * SEQLEN)
#define EPSF 1e-6f

// async global->LDS, 16B per lane. LDS dest must be wave-uniform base + lane*16.
__device__ inline void gload_lds16(const void* g, void* l) {
  __builtin_amdgcn_global_load_lds((__attribute__((address_space(1))) void*)(g),
                                   (__attribute__((address_space(3))) void*)(l),
                                   16, 0, 0);
}

// ---------------------------------------------------------------------------
// fused dual f32 -> bf16 convert (two independent tensors, one launch)
// ---------------------------------------------------------------------------
__global__ __launch_bounds__(256) void cvt2_f32_bf16(
    const float* __restrict__ a, bf16* __restrict__ da, int na4,
    const float* __restrict__ b, bf16* __restrict__ db, int nb4) {
  int j = blockIdx.x * 256 + threadIdx.x;
  const float* s;
  bf16* d;
  if (j < na4) {
    s = a; d = da;
  } else {
    j -= na4;
    if (j >= nb4) return;
    s = b; d = db;
  }
  const float4 v = ((const float4*)s)[j];
  bf16x4 o;
  o[0] = (bf16)v.x; o[1] = (bf16)v.y; o[2] = (bf16)v.z; o[3] = (bf16)v.w;
  ((bf16x4*)d)[j] = o;
}

__global__ __launch_bounds__(256) void cvt_f32_bf16(
    const float* __restrict__ src, bf16* __restrict__ dst, int n4) {
  const int i = blockIdx.x * 256 + threadIdx.x;
  if (i < n4) {
    const float4 v = ((const float4*)src)[i];
    bf16x4 o;
    o[0] = (bf16)v.x; o[1] = (bf16)v.y; o[2] = (bf16)v.z; o[3] = (bf16)v.w;
    ((bf16x4*)dst)[i] = o;
  }
}

// ---------------------------------------------------------------------------
// GEMM: C[m,n] = sum_k A[m,k]*W[n,k] + bias[n] (+ skip[m,n]); A (M,K), W (N,K)
// m97 pattern, TM x TN tile, BK=32, 4 waves in 2x2; global_load_lds x16.
// ---------------------------------------------------------------------------
template <int TM, int TN, int NCOLS, bool ADD_SKIP, typename CT>
__global__ __launch_bounds__(256) void gemm_bt(
    const bf16* __restrict__ A, const bf16* __restrict__ W,
    const float* __restrict__ bias, const float* __restrict__ skip,
    CT* __restrict__ C, int K) {
  constexpr int MI = TM / 32;  // m-frags per wave
  constexpr int NI = TN / 32;  // n-frags per wave
  __shared__ __align__(16) bf16 As[TM * 32];
  __shared__ __align__(16) bf16 Bs[TN * 32];
  const int t = threadIdx.x;
  const int lane = t & 63, w = t >> 6;
  const int wm = (w >> 1) * (TM / 2), wn = (w & 1) * (TN / 2);
  const int row16 = lane & 15, quad = lane >> 4;
  const int m0 = blockIdx.x * TM, n0 = blockIdx.y * TN;

  f32x4 zero4 = {0.f, 0.f, 0.f, 0.f};
  f32x4 acc[MI][NI];
#pragma unroll
  for (int mi = 0; mi < MI; ++mi)
#pragma unroll
    for (int ni = 0; ni < NI; ++ni) acc[mi][ni] = zero4;

  const int arow = t >> 2;
  const int acol = (t & 3) * 8;
  const bf16* Ab = A + (size_t)m0 * K;
  const bf16* Wb = W + (size_t)n0 * K;

  for (int kt = 0; kt < K; kt += 32) {
    gload_lds16(Ab + (size_t)arow * K + kt + acol, As + t * 8);
    if (TM == 128)
      gload_lds16(Ab + (size_t)(64 + arow) * K + kt + acol, As + 2048 + t * 8);
    gload_lds16(Wb + (size_t)arow * K + kt + acol, Bs + t * 8);
    if (TN == 128)
      gload_lds16(Wb + (size_t)(64 + arow) * K + kt + acol, Bs + 2048 + t * 8);
    __syncthreads();

    bf16x8 af[MI], wf[NI];
#pragma unroll
    for (int mi = 0; mi < MI; ++mi)
      af[mi] = *(const bf16x8*)&As[(wm + mi * 16 + row16) * 32 + quad * 8];
#pragma unroll
    for (int ni = 0; ni < NI; ++ni)
      wf[ni] = *(const bf16x8*)&Bs[(wn + ni * 16 + row16) * 32 + quad * 8];
#pragma unroll
    for (int mi = 0; mi < MI; ++mi)
#pragma unroll
      for (int ni = 0; ni < NI; ++ni)
        acc[mi][ni] = __builtin_amdgcn_mfma_f32_16x16x32_bf16(
            af[mi], wf[ni], acc[mi][ni], 0, 0, 0);
    __syncthreads();
  }

#pragma unroll
  for (int mi = 0; mi < MI; ++mi) {
#pragma unroll
    for (int ni = 0; ni < NI; ++ni) {
      const int col = n0 + wn + ni * 16 + row16;
      const float bv = bias[col];
#pragma unroll
      for (int r = 0; r < 4; ++r) {
        const int row = m0 + wm + mi * 16 + quad * 4 + r;
        float v = acc[mi][ni][r] + bv;
        if (ADD_SKIP) v += skip[(size_t)row * NCOLS + col];
        C[(size_t)row * NCOLS + col] = (CT)v;
      }
    }
  }
}

// ---------------------------------------------------------------------------
// Q+K+V causal width-3 conv from u:
//   ch 0..15  -> Q (B,N,L,16);  16..31 -> K (B,N,L,16);  32..47 -> V (B,N,16,L)
// ---------------------------------------------------------------------------
__global__ __launch_bounds__(256) void conv_qkv(
    const bf16* __restrict__ u, const float* __restrict__ w_sf,
    const float* __restrict__ b_sf, bf16* __restrict__ qq,
    bf16* __restrict__ kk, bf16* __restrict__ vv) {
  const int nh = blockIdx.x, b = blockIdx.y, lc = blockIdx.z;
  const int l0 = lc * 128;
  __shared__ __align__(8) bf16 ut[130 * 48];
  const int t = threadIdx.x;
  for (int i = t; i < 130 * 12; i += 256) {
    const int lr = i / 12, qd = i % 12;
    const int l = l0 - 2 + lr;
    uint2 val;
    val.x = 0u; val.y = 0u;
    if (l >= 0)
      val = *(const uint2*)&u[(size_t)(b * SEQLEN + l) * INNER + nh * 48 + qd * 4];
    *(uint2*)&ut[lr * 48 + qd * 4] = val;
  }
  __syncthreads();
  const size_t bn = (size_t)(b * NUM_HEADS + nh);
#pragma unroll
  for (int s = 0; s < 2; ++s) {
    bf16* dst = (s == 0) ? qq : kk;
    const int cb = s * 16;
    for (int i = t; i < 128 * 16; i += 256) {
      const int c = i & 15, lr = i >> 4;
      const int e = nh * 48 + cb + c;
      const float val = w_sf[e * 3 + 0] * (float)ut[lr * 48 + cb + c] +
                        w_sf[e * 3 + 1] * (float)ut[(lr + 1) * 48 + cb + c] +
                        w_sf[e * 3 + 2] * (float)ut[(lr + 2) * 48 + cb + c] +
                        b_sf[e];
      dst[(bn * SEQLEN + l0 + lr) * 16 + c] = (bf16)val;
    }
  }
  for (int i = t; i < 128 * 16; i += 256) {
    const int lr = i & 127, c = i >> 7;
    const int e = nh * 48 + 32 + c;
    const float val = w_sf[e * 3 + 0] * (float)ut[lr * 48 + 32 + c] +
                      w_sf[e * 3 + 1] * (float)ut[(lr + 1) * 48 + 32 + c] +
                      w_sf[e * 3 + 2] * (float)ut[(lr + 2) * 48 + 32 + c] +
                      b_sf[e];
    vv[(bn * 16 + c) * SEQLEN + l0 + lr] = (bf16)val;
  }
}

// ---------------------------------------------------------------------------
// Causal h-weighted attention v7 = r9 structure with the causal mask folded
// into a zero-padded LDS h table (hs[32+d] = h[d], hs[i<32] = 0): deletes
// 16 cmp + 16 cndmask per K-step. h reads ascending -> ds_read2_b32 pairs.
// One 32-row Q tile/block, KV split 4 ways across waves (6144 blocks).
// S^T = mfma_32x32x16(K,Q); S->A via LDS round-trip; PV = 2x mfma_16x16x32.
// ---------------------------------------------------------------------------
__global__ __launch_bounds__(256) void attn_kernel(
    const bf16* __restrict__ qq, const bf16* __restrict__ kk,
    const bf16* __restrict__ vv, const float* __restrict__ hg,
    float* __restrict__ y) {
  const int nh = blockIdx.x, b = blockIdx.y;
  const int q32 = (int)gridDim.z - 1 - (int)blockIdx.z;  // big tiles first
  const int l0 = q32 * 32;
  __shared__ __align__(16) float hs[32 + SEQLEN];  // hs[32+d]=h[d], pad=0
  __shared__ __align__(16) bf16 st[4 * 32 * 40];   // per-wave S-tile / O-redux
  const int t = threadIdx.x;
  // fill hs[0 .. l0+64): 8 zero-float4s then h[0 .. l0+32)
  const int n4 = (l0 + 64) >> 2;
  for (int i = t; i < n4; i += 256) {
    float4 val = {0.f, 0.f, 0.f, 0.f};
    if (i >= 8) val = ((const float4*)(hg + nh * SEQLEN))[i - 8];
    ((float4*)hs)[i] = val;
  }
  __syncthreads();

  const int w = t >> 6, lane = t & 63;
  const int l31 = lane & 31, hi = lane >> 5;
  const int row16 = lane & 15, quad = lane >> 4;
  const size_t bn = (size_t)(b * NUM_HEADS + nh);
  const bf16* qb = qq + bn * SEQLEN * 16;
  const bf16* kb = kk + bn * SEQLEN * 16;
  const bf16* vb = vv + bn * 16 * SEQLEN;

  bf16x8 zf;
#pragma unroll
  for (int j = 0; j < 8; ++j) zf[j] = (bf16)0.f;
  const f32x4 zacc4 = {0.f, 0.f, 0.f, 0.f};
  f32x16 zacc16;
#pragma unroll
  for (int j = 0; j < 16; ++j) zacc16[j] = 0.f;

  // Q B-operand frag: lane l31 holds Q[l0+l31][ch hi*8..+8]
  const bf16x8 qf = *(const bf16x8*)&qb[(l0 + l31) * 16 + hi * 8];

  f32x4 o0 = zacc4, o1 = zacc4;
  bf16* sw = &st[w * 32 * 40];

  int mc = w * 32;
  bf16x8 kf = zf, vf = zf;
  if (mc <= l0) {
    kf = *(const bf16x8*)&kb[(mc + l31) * 16 + hi * 8];
    vf = *(const bf16x8*)&vb[row16 * SEQLEN + mc + quad * 8];
  }
  for (; mc <= l0; mc += 128) {
    const int mn = mc + 128;
    bf16x8 kf2 = zf, vf2 = zf;
    if (mn <= l0) {  // prefetch next chunk
      kf2 = *(const bf16x8*)&kb[(mn + l31) * 16 + hi * 8];
      vf2 = *(const bf16x8*)&vb[row16 * SEQLEN + mn + quad * 8];
    }
    // S^T[m-local=rows][l-local=cols] = sum_ch K*Q
    f32x16 s = __builtin_amdgcn_mfma_f32_32x32x16_bf16(kf, qf, zacc16, 0, 0, 0);

    // h-weight; causal mask is free via zero pad. reg j -> hp[3-j], ascending
    // hp offsets 0..3 merge into ds_read2_b32 pairs.
    const int d0 = 32 + (l0 - mc) + l31 - 4 * hi;
#pragma unroll
    for (int g = 0; g < 4; ++g) {
      const float* hp = &hs[d0 - 8 * g - 3];
      bf16x4 pk;
      pk[0] = (bf16)(s[4 * g + 0] * hp[3]);
      pk[1] = (bf16)(s[4 * g + 1] * hp[2]);
      pk[2] = (bf16)(s[4 * g + 2] * hp[1]);
      pk[3] = (bf16)(s[4 * g + 3] * hp[0]);
      *(bf16x4*)&sw[l31 * 40 + 8 * g + 4 * hi] = pk;
    }
    asm volatile("s_waitcnt lgkmcnt(0)" ::: "memory");  // stores before reads
    // PV: A = S[l][m] (b128), B = V[m][j] frag (shared by both halves)
    const bf16x8 sf0 = *(const bf16x8*)&sw[row16 * 40 + quad * 8];
    const bf16x8 sf1 = *(const bf16x8*)&sw[(row16 + 16) * 40 + quad * 8];
    o0 = __builtin_amdgcn_mfma_f32_16x16x32_bf16(sf0, vf, o0, 0, 0, 0);
    o1 = __builtin_amdgcn_mfma_f32_16x16x32_bf16(sf1, vf, o1, 0, 0, 0);
    asm volatile("" ::: "memory");  // reads before next-iter stores
    kf = kf2; vf = vf2;
  }

  // per-wave O into own LDS region (f32 32x16), then block reduce
  float* ob = (float*)&st[w * 32 * 40];
#pragma unroll
  for (int r = 0; r < 4; ++r) {
    ob[(quad * 4 + r) * 16 + row16] = o0[r];
    ob[(quad * 4 + r + 16) * 16 + row16] = o1[r];
  }
  __syncthreads();
  for (int i = t; i < 32 * 16; i += 256) {
    const int l = i >> 4, j = i & 15;
    float sum = 0.f;
#pragma unroll
    for (int ww = 0; ww < 4; ++ww)
      sum += ((const float*)&st[ww * 32 * 40])[l * 16 + j];
    y[((size_t)(b * SEQLEN + l0 + l) * NUM_HEADS + nh) * 16 + j] = sum;
  }
}

// ---------------------------------------------------------------------------
// RMSNorm over D=768 per row: y f32 in, yn bf16 out, * norm_w (f32)
// ---------------------------------------------------------------------------
__global__ __launch_bounds__(256) void rmsnorm_k(
    const float* __restrict__ y, const float* __restrict__ nw,
    bf16* __restrict__ yn) {
  const int row = blockIdx.x;
  const int t = threadIdx.x;
  const float* yr = y + (size_t)row * D_MODEL;
  const float v0 = yr[t];
  const float v1 = yr[t + 256];
  const float v2 = yr[t + 512];
  float ss = v0 * v0 + v1 * v1 + v2 * v2;
#pragma unroll
  for (int off = 32; off >= 1; off >>= 1) ss += __shfl_down(ss, off, 64);
  __shared__ float red[4];
  if ((t & 63) == 0) red[t >> 6] = ss;
  __syncthreads();
  const float tot = red[0] + red[1] + red[2] + red[3];
  const float r = rsqrtf(tot * (1.f / 768.f) + EPSF);
  bf16* yo = yn + (size_t)row * D_MODEL;
  yo[t] = (bf16)(v0 * r * nw[t]);
  yo[t + 256] = (bf16)(v1 * r * nw[t + 256]);
  yo[t + 512] = (bf16)(v2 * r * nw[t + 512]);
}

// ---------------------------------------------------------------------------
extern "C" void kernel_launch(void* const* d_in, const int* in_sizes, int n_in,
                              void* d_out, int out_size, void* d_ws,
                              size_t ws_size, hipStream_t stream) {
  const float* inputs = (const float*)d_in[0];
  const float* w_in = (const float*)d_in[1];
  const float* b_in = (const float*)d_in[2];
  const float* w_sf = (const float*)d_in[3];
  const float* b_sf = (const float*)d_in[4];
  const float* hb = (const float*)d_in[5];
  const float* norm_w = (const float*)d_in[6];
  const float* w_out = (const float*)d_in[7];
  const float* b_out = (const float*)d_in[8];

  // ws plan (37.8 MB), region lifetimes:
  //   u   18.9 MB : GEMM1 out -> dead after conv_qkv; tail reused for
  //                 wout16 (at +0) and yn (at +2MB) late in the pipeline
  //   v    6.3 MB : V
  //   A    6.3 MB : in16 (GEMM1 A) -> k16 (attn) -> dead
  //   B    6.3 MB : win16 (GEMM1 W, 3.5MB) -> q16 (attn)
  char* ws = (char*)d_ws;
  const size_t U_B = (size_t)M_ROWS * INNER * 2;
  const size_t V_B = (size_t)BATCH * NUM_HEADS * HEAD_CH * SEQLEN * 2;
  const size_t SLOT_B = (size_t)M_ROWS * D_MODEL * 2;
  bf16* u = (bf16*)(ws);
  bf16* wout16 = (bf16*)(ws);                    // u region, after conv
  bf16* yn = (bf16*)(ws + (2 << 20));            // u region +2MB (wout=1.2MB)
  bf16* v = (bf16*)(ws + U_B);
  bf16* in16 = (bf16*)(ws + U_B + V_B);          // A
  bf16* k16 = in16;                              // A after GEMM1
  bf16* win16 = (bf16*)(ws + U_B + V_B + SLOT_B);// B
  bf16* q16 = win16;                             // B after GEMM1
  float* y = (float*)d_out;
  float* out = (float*)d_out;

  const int n4_in = M_ROWS * D_MODEL / 4;
  const int n4_win = INNER * D_MODEL / 4;
  const int n4_wout = D_MODEL * D_MODEL / 4;
  hipLaunchKernelGGL(cvt2_f32_bf16, dim3((n4_in + n4_win + 255) / 256),
                     dim3(256), 0, stream, inputs, in16, n4_in, w_in, win16,
                     n4_win);

  hipLaunchKernelGGL((gemm_bt<128, 128, INNER, false, bf16>), dim3(32, 18),
                     dim3(256), 0, stream, in16, win16, b_in,
                     (const float*)nullptr, u, 768);
  hipLaunchKernelGGL(conv_qkv, dim3(48, 2, 16), dim3(256), 0, stream, u, w_sf,
                     b_sf, q16, k16, v);
  // u dead now: stage w_out into its head
  hipLaunchKernelGGL(cvt_f32_bf16, dim3((n4_wout + 255) / 256), dim3(256), 0,
                     stream, w_out, wout16, n4_wout);
  hipLaunchKernelGGL(attn_kernel, dim3(48, 2, 64), dim3(256), 0, stream, q16,
                     k16, v, hb, y);
  hipLaunchKernelGGL(rmsnorm_k, dim3(M_ROWS), dim3(256), 0, stream, y, norm_w,
                     yn);
  hipLaunchKernelGGL((gemm_bt<64, 64, D_MODEL, true, float>), dim3(64, 12),
                     dim3(256), 0, stream, yn, wout16, b_out, inputs, out,
                     768);
}